// Round 13
// baseline (58.858 us; speedup 1.0000x reference)
//
#include <hip/hip_runtime.h>
#include <math.h>

namespace {
constexpr int N_ = 2048;
constexpr int D_ = 128;
constexpr int K_ = 8;
constexpr int M_ = 64;
constexpr float JIT = 1e-5f;
constexpr float L2E = 1.4426950408889634f;
constexpr float LN2 = 0.6931471805599453f;

// ws float offsets. bar region: 16 ints at ws[0..16), zeroed by K1 block 0.
//   bar[g], g in [0,8) : psi2 slice-group counters (target 16 chunks each)
constexpr int OFF_ARR2 = 16;                    // N*16 : per-n [a[8], ib2s[8]]
constexpr int OFF_C2   = OFF_ARR2 + N_ * 16;    // N
constexpr int OFF_P2P  = OFF_C2 + N_;           // 16*4096 psi2 partials
constexpr int OFF_P1Y  = OFF_P2P + 16 * 4096;   // 8*64
constexpr int OFF_KUI  = OFF_P1Y + 512;         // 4096 : -Kuu^{-1}
constexpr int OFF_SC   = OFF_KUI + 4096;        // 3 : YY, KL, log2det(Kuu)
}

struct F8 { float f[8]; };

// ---- barrier primitives ----------------------------------------------------
__device__ __forceinline__ void bar_arrive(int* c) {
  __syncthreads();
  if (threadIdx.x == 0) { __threadfence(); atomicAdd(c, 1); }
}
template <int SLP>
__device__ __forceinline__ void bar_wait(int* c, int target) {
  if (threadIdx.x == 0) {
    while (__hip_atomic_load(c, __ATOMIC_RELAXED, __HIP_MEMORY_SCOPE_AGENT) < target)
      __builtin_amdgcn_s_sleep(SLP);
    __threadfence();
  }
  __syncthreads();
}

// ---------------------------------------------------------------------------
// 4-wave software-pipelined 2x2-block symmetric sweep (verified r12).
//   reg[r] = A[16*wave + r][lane]  ->  (-A^{-1})[16*wave + r][lane]
// Returns log2(det A), identical in every thread.
// ---------------------------------------------------------------------------
__device__ __forceinline__ float sweep2x2_pipe(
    float* reg, float (*rowbuf)[2][M_], int wave, int lane) {
  if (wave == 0) {
    rowbuf[0][0][lane] = reg[0];
    rowbuf[0][1][lane] = reg[1];
  }
  __syncthreads();
  float ld = 0.f;
#pragma unroll
  for (int s = 0; s < 32; ++s) {
    const int p = 2 * s;
    const int par = s & 1;
    float* rbA = rowbuf[par][0];
    float* rbB = rowbuf[par][1];
    const int own_s  = s >> 3;
    const int own_s1 = (s + 1) >> 3;
    const int rp  = p & 15;
    const int rp2 = (p + 2) & 15;

    const float P00 = rbA[p];
    const float P01 = rbA[p + 1];
    const float P11 = rbB[p + 1];
    const float a0  = rbA[lane];
    const float a1  = rbB[lane];
    const float det = fmaf(P00, P11, -P01 * P01);
    const float idet = __builtin_amdgcn_rcpf(det);
    ld += __log2f(det);
    const float Pi00 =  P11 * idet;
    const float Pi01 = -P01 * idet;
    const float Pi11 =  P00 * idet;

    const bool isp = (lane == p), isq = (lane == p + 1);
    const float w0 = isp ? Pi00 : (isq ? Pi01 : fmaf(Pi00, a0, Pi01 * a1));
    const float w1 = isp ? Pi01 : (isq ? Pi11 : fmaf(Pi01, a0, Pi11 * a1));
    const float t0 = isp ? (1.f - w0) : (isq ? -w0 : w0);
    const float t1 = isq ? (1.f - w1) : (isp ? -w1 : w1);
    const float f0 = (isp || isq) ? -w0 : w0;
    const float f1 = (isp || isq) ? -w1 : w1;

    if (s < 31 && wave == own_s1) {
      const float e0 = fmaf(-t1, rbB[p + 2], fmaf(-t0, rbA[p + 2], reg[rp2]));
      const float e1 = fmaf(-t1, rbB[p + 3], fmaf(-t0, rbA[p + 3], reg[rp2 + 1]));
      rowbuf[par ^ 1][0][lane] = e0;
      rowbuf[par ^ 1][1][lane] = e1;
    }

    const float4* rAq = reinterpret_cast<const float4*>(rbA + 16 * wave);
    const float4* rBq = reinterpret_cast<const float4*>(rbB + 16 * wave);
#pragma unroll
    for (int q = 0; q < 4; q++) {
      const float4 va = rAq[q], vb = rBq[q];
      reg[4 * q + 0] = fmaf(-t1, vb.x, fmaf(-t0, va.x, reg[4 * q + 0]));
      reg[4 * q + 1] = fmaf(-t1, vb.y, fmaf(-t0, va.y, reg[4 * q + 1]));
      reg[4 * q + 2] = fmaf(-t1, vb.z, fmaf(-t0, va.z, reg[4 * q + 2]));
      reg[4 * q + 3] = fmaf(-t1, vb.w, fmaf(-t0, va.w, reg[4 * q + 3]));
    }
    if (wave == own_s) { reg[rp] = f0; reg[rp + 1] = f1; }
    __syncthreads();
  }
  return ld;
}

// ---------------------------------------------------------------------------
// K1: 10 blocks.
//   b<8 : prep chunk b (stats -> ws) + fused Psi1^T Y partial (LDS-resident)
//   b==8: pipelined Kuu^{-1} sweep -> ws.  b==9: YY + KL -> ws.
// Block 0 zeroes the 16 barrier ints (K2 is stream-ordered after K1).
// ---------------------------------------------------------------------------
__global__ __launch_bounds__(256) void vdmgp_k1(
    const float* __restrict__ X, const float* __restrict__ Y,
    const float* __restrict__ qmu, const float* __restrict__ qcov,
    const float* __restrict__ Z, float* __restrict__ ws) {
  __shared__ float smu[D_ * K_];   // [d][k]
  __shared__ float scov[D_ * K_];
  __shared__ float sa1[256 * 16];
  __shared__ float scy[256];
  __shared__ float red[256];
  __shared__ float zl[M_][9];
  __shared__ __align__(16) float rowbuf[2][2][M_];
  const int tid = threadIdx.x;
  const int b = blockIdx.x;

  if (b == 0 && tid < 16) ((int*)ws)[tid] = 0;

  if (b == 8) {
    for (int idx = tid; idx < M_ * K_; idx += 256) zl[idx >> 3][idx & 7] = Z[idx];
    __syncthreads();
    const int lane = tid & 63;
    const int wave = tid >> 6;
    float zj[K_];
#pragma unroll
    for (int k = 0; k < K_; k++) zj[k] = zl[lane][k];
    float reg[16];
#pragma unroll
    for (int r = 0; r < 16; r++) {
      const int gi = 16 * wave + r;
      float sq = 0.f;
#pragma unroll
      for (int k = 0; k < K_; k++) { const float dd = zl[gi][k] - zj[k]; sq = fmaf(dd, dd, sq); }
      reg[r] = exp2f(-0.5f * L2E * sq) + ((gi == lane) ? JIT : 0.f);
    }
    const float ld1 = sweep2x2_pipe(reg, rowbuf, wave, lane);
#pragma unroll
    for (int r = 0; r < 16; r++)
      ws[OFF_KUI + (16 * wave + r) * 64 + lane] = reg[r];   // -Kuu^{-1}
    if (tid == 0) ws[OFF_SC + 2] = LN2 * ld1;
    return;
  }

  if (b == 9) {
    const int lane = tid & 63;
    const int wave = tid >> 6;
    if (wave == 0) {
      float yy = 0.f;
#pragma unroll
      for (int t = 0; t < 32; t++) {
        const float y = Y[t * 64 + lane];
        yy = fmaf(y, y, yy);
      }
#pragma unroll
      for (int off = 32; off > 0; off >>= 1) yy += __shfl_down(yy, off, 64);
      if (lane == 0) ws[OFF_SC + 0] = yy;
    } else if (wave == 1) {
      const int k = lane >> 3;
      const int d0 = (lane & 7) * 16;
      float slog = 0.f, srow = 0.f;
#pragma unroll
      for (int t = 0; t < 16; t++) {
        const float qc = qcov[k * D_ + d0 + t];
        const float qm = qmu[k * D_ + d0 + t];
        slog += logf(qc);
        srow += qc + qm * qm;
      }
#pragma unroll
      for (int off = 4; off > 0; off >>= 1) {
        slog += __shfl_down(slog, off, 8);
        srow += __shfl_down(srow, off, 8);
      }
      float klr = ((lane & 7) == 0)
          ? (slog - (float)D_ * logf(srow) + (float)D_ * logf((float)D_)) : 0.f;
      klr += __shfl_down(klr, 32, 64);
      klr += __shfl_down(klr, 16, 64);
      klr += __shfl_down(klr, 8, 64);
      if (lane == 0) ws[OFF_SC + 1] = klr;
    }
    return;
  }

  // ---- prep chunk b + fused p1y (r2-verified pattern) ----
  for (int idx = tid; idx < K_ * D_; idx += 256) {
    int k = idx >> 7, d = idx & 127;
    smu[d * K_ + k]  = qmu[idx];
    scov[d * K_ + k] = qcov[idx];
  }
  __syncthreads();

  const int n = b * 256 + tid;
  float a[K_], s2[K_];
#pragma unroll
  for (int k = 0; k < K_; k++) { a[k] = 0.f; s2[k] = 0.f; }

  const float4* xrow = reinterpret_cast<const float4*>(X + n * D_);
  for (int dq = 0; dq < D_ / 4; dq++) {
    float4 xv = xrow[dq];
    float xs[4] = {xv.x, xv.y, xv.z, xv.w};
#pragma unroll
    for (int t = 0; t < 4; t++) {
      const int d = dq * 4 + t;
      const float x = xs[t];
      const float xx = x * x;
      F8 mu = *reinterpret_cast<const F8*>(&smu[d * K_]);
      F8 cv = *reinterpret_cast<const F8*>(&scov[d * K_]);
#pragma unroll
      for (int k = 0; k < K_; k++) {
        a[k]  = fmaf(mu.f[k], x, a[k]);
        s2[k] = fmaf(cv.f[k], xx, s2[k]);
      }
    }
  }

  float4 w2[4];
  float prod2 = 1.f, prod1 = 1.f;
#pragma unroll
  for (int k = 0; k < K_; k++) {
    const float b2 = 2.f * s2[k] + 1.f;
    const float b1 = 1.f + s2[k];
    reinterpret_cast<float*>(w2)[k]     = a[k];
    reinterpret_cast<float*>(w2)[8 + k] = L2E / b2;
    sa1[tid * 16 + k]     = a[k];
    sa1[tid * 16 + 8 + k] = 0.5f * L2E / b1;
    prod2 *= rsqrtf(b2);
    prod1 *= rsqrtf(b1);
  }
  float4* a2q = reinterpret_cast<float4*>(ws + OFF_ARR2 + n * 16);
#pragma unroll
  for (int e = 0; e < 4; e++) a2q[e] = w2[e];
  (ws + OFF_C2)[n] = prod2;
  scy[tid] = prod1 * Y[n];
  __syncthreads();

  // Psi1^T Y over this block's 256 n's (LDS resident)
  const int m = tid & 63;
  const int stripe = tid >> 6;
  float zm[K_];
#pragma unroll
  for (int k = 0; k < K_; k++) zm[k] = Z[m * K_ + k];
  float acc = 0.f;
  for (int t = 0; t < 64; t++) {
    const int nl = stripe * 64 + t;
    const F8 av = *reinterpret_cast<const F8*>(&sa1[nl * 16]);
    const F8 ib = *reinterpret_cast<const F8*>(&sa1[nl * 16 + 8]);
    float s = 0.f;
#pragma unroll
    for (int k = 0; k < K_; k++) {
      const float d = av.f[k] - zm[k];
      s = fmaf(d * d, ib.f[k], s);
    }
    acc = fmaf(scy[nl], exp2f(-s), acc);
  }
  red[tid] = acc;
  __syncthreads();
  if (tid < 64)
    (ws + OFF_P1Y)[b * 64 + tid] =
        red[tid] + red[64 + tid] + red[128 + tid] + red[192 + tid];
}

// ---------------------------------------------------------------------------
// K2: 129 blocks, ONE sync hop (workers -> tail).
//   b>=1, w=b-1 : psi2 worker. chunk = w>>3 (128 n staged once), slice-group
//                 sg = w&7 -> pair-slices {2sg, 2sg+1}. Arrive bar[sg].
//   b==0        : tail. Preload zl/base/left/kui/pys -> wait bar[0..8)==16 ->
//                 reduce own partial slice (fold left) -> pipelined A2 sweep
//                 -> quad + trace -> combine -> out[0].
// ---------------------------------------------------------------------------
__global__ __launch_bounds__(256) void vdmgp_k2(
    const float* __restrict__ Z,
    const float* __restrict__ sfp, const float* __restrict__ nvp,
    float* __restrict__ ws, float* __restrict__ out) {
  __shared__ __align__(16) float pool[2432];

  int* bar = (int*)ws;
  const int tid = threadIdx.x;
  const int b = blockIdx.x;
  const float sf = sfp[0];

  if (b > 0) {
    const int w = b - 1;
    const int chunk = w >> 3;
    const int sg = w & 7;
    float* sa = pool;           // 128*16
    float* sc = pool + 2048;    // 128
    const int nbase = chunk * 128;
    {
      const float4* src = reinterpret_cast<const float4*>(ws + OFF_ARR2 + nbase * 16);
      float4* dst = reinterpret_cast<float4*>(sa);
      for (int idx = tid; idx < 512; idx += 256) dst[idx] = src[idx];
      if (tid < 128) sc[tid] = (ws + OFF_C2)[nbase + tid];
    }
    __syncthreads();

    const int pa = (2 * sg) * 256 + tid;      // pair in slice 2sg
    const int pb = pa + 256;                  // pair in slice 2sg+1
    const int ia = pa >> 6, ja = pa & 63;
    const int ib_ = pb >> 6, jb = pb & 63;
    float zba[K_], zbb[K_];
#pragma unroll
    for (int k = 0; k < K_; k++) {
      zba[k] = 0.5f * (Z[ia * K_ + k] + Z[ja * K_ + k]);
      zbb[k] = 0.5f * (Z[ib_ * K_ + k] + Z[jb * K_ + k]);
    }

    float acca = 0.f, accb = 0.f;
    for (int nl = 0; nl < 128; nl += 2) {
      const F8 av0 = *reinterpret_cast<const F8*>(&sa[nl * 16]);
      const F8 ib0 = *reinterpret_cast<const F8*>(&sa[nl * 16 + 8]);
      const F8 av1 = *reinterpret_cast<const F8*>(&sa[(nl + 1) * 16]);
      const F8 ib1 = *reinterpret_cast<const F8*>(&sa[(nl + 1) * 16 + 8]);
      float s0a = 0.f, s0b = 0.f, s1a = 0.f, s1b = 0.f;
#pragma unroll
      for (int k = 0; k < K_; k++) {
        const float da0 = av0.f[k] - zba[k]; s0a = fmaf(da0 * da0, ib0.f[k], s0a);
        const float db0 = av0.f[k] - zbb[k]; s0b = fmaf(db0 * db0, ib0.f[k], s0b);
        const float da1 = av1.f[k] - zba[k]; s1a = fmaf(da1 * da1, ib1.f[k], s1a);
        const float db1 = av1.f[k] - zbb[k]; s1b = fmaf(db1 * db1, ib1.f[k], s1b);
      }
      acca = fmaf(sc[nl], exp2f(-s0a), acca);
      accb = fmaf(sc[nl], exp2f(-s0b), accb);
      acca = fmaf(sc[nl + 1], exp2f(-s1a), acca);
      accb = fmaf(sc[nl + 1], exp2f(-s1b), accb);
    }
    (ws + OFF_P2P)[chunk * 4096 + pa] = acca;
    (ws + OFF_P2P)[chunk * 4096 + pb] = accb;
    bar_arrive(&bar[sg]);
    return;
  }

  // -------- b == 0: tail --------
  float (*zl)[9]         = reinterpret_cast<float(*)[9]>(pool);            // 576
  float (*rowbuf)[2][M_] = reinterpret_cast<float(*)[2][M_]>(pool + 576);  // 256
  float* pysL  = pool + 832;                                               // 64
  float* scalL = pool + 896;                                               // 8
  float* redQ  = pool + 912;                                               // 256
  float* redT  = pool + 1168;                                              // 256

  const int lane = tid & 63;
  const int wave = tid >> 6;
  const float s2v = nvp[0];
  const float sf2 = sf * sf;

  for (int idx = tid; idx < M_ * K_; idx += 256) zl[idx >> 3][idx & 7] = Z[idx];
  if (tid < M_) {
    float s = 0.f;
#pragma unroll
    for (int c = 0; c < 8; c++) s += ws[OFF_P1Y + c * M_ + tid];
    pysL[tid] = sf * s;
  }
  __syncthreads();

  // preload: one exp2 gives both Kuu (e^2) and left (sf^2 * e)
  float zj[K_];
#pragma unroll
  for (int k = 0; k < K_; k++) zj[k] = zl[lane][k];
  float base[16], leftf[16], kui16[16];
#pragma unroll
  for (int r = 0; r < 16; r++) {
    const int gi = 16 * wave + r;
    float sq = 0.f;
#pragma unroll
    for (int k = 0; k < K_; k++) { const float dd = zl[gi][k] - zj[k]; sq = fmaf(dd, dd, sq); }
    const float e = exp2f(-0.25f * L2E * sq);
    const float jit = (gi == lane) ? JIT : 0.f;
    base[r]  = fmaf(s2v, e * e + jit, jit);
    leftf[r] = sf2 * e;
    kui16[r] = ws[OFF_KUI + gi * 64 + lane];
  }

#pragma unroll
  for (int g = 0; g < 8; g++) bar_wait<2>(&bar[g], 16);

  // reduce own slice of partials, fold left; build A2 rows + trace partial
  float reg[16];
  float sT = 0.f;
#pragma unroll
  for (int r = 0; r < 16; r++) {
    const int pidx = (16 * wave + r) * 64 + lane;
    float s = 0.f;
#pragma unroll
    for (int c = 0; c < 16; c++) s += ws[OFF_P2P + c * 4096 + pidx];
    const float p2v = leftf[r] * s;
    reg[r] = base[r] + p2v;
    sT = fmaf(kui16[r], p2v, sT);
  }
  redT[tid] = sT;

  const float ld2 = sweep2x2_pipe(reg, rowbuf, wave, lane);

  float sQ = 0.f;
#pragma unroll
  for (int r = 0; r < 16; r++) sQ = fmaf(reg[r], pysL[16 * wave + r], sQ);
  redQ[tid] = sQ;
  __syncthreads();

  if (wave == 0) {
    float c = redQ[lane] + redQ[64 + lane] + redQ[128 + lane] + redQ[192 + lane];
    float q = c * pysL[lane];
#pragma unroll
    for (int off = 32; off > 0; off >>= 1) q += __shfl_down(q, off, 64);
    if (lane == 0) scalL[7] = -q;    // quad
  } else if (wave == 1) {
    float s = redT[lane] + redT[64 + lane] + redT[128 + lane] + redT[192 + lane];
#pragma unroll
    for (int off = 32; off > 0; off >>= 1) s += __shfl_down(s, off, 64);
    if (lane == 0) scalL[5] = -s;    // trace
  }
  __syncthreads();

  if (tid == 0) {
    const float YY  = ws[OFF_SC + 0];
    const float KL  = ws[OFF_SC + 1];
    const float ld1 = ws[OFF_SC + 2];
    const float tr = scalL[5], quad = scalL[7];
    const float inv = 1.0f / s2v;
    const float F1 = -(float)N_ * 1.8378770664093453f
                   - (float)(N_ - M_) * logf(s2v)
                   + (ld1 - LN2 * ld2)
                   - YY * inv
                   + quad * inv
                   - (float)N_ * sf2 * inv
                   + tr * inv;
    out[0] = 0.5f * (F1 + KL);
  }
}

extern "C" void kernel_launch(void* const* d_in, const int* in_sizes, int n_in,
                              void* d_out, int out_size, void* d_ws, size_t ws_size,
                              hipStream_t stream) {
  const float* X    = (const float*)d_in[0];
  const float* Y    = (const float*)d_in[1];
  const float* qmu  = (const float*)d_in[2];
  const float* qcov = (const float*)d_in[3];
  const float* Z    = (const float*)d_in[4];
  const float* sfp  = (const float*)d_in[5];
  const float* nvp  = (const float*)d_in[6];
  float* ws  = (float*)d_ws;
  float* out = (float*)d_out;

  vdmgp_k1<<<10, 256, 0, stream>>>(X, Y, qmu, qcov, Z, ws);
  vdmgp_k2<<<129, 256, 0, stream>>>(Z, sfp, nvp, ws, out);
}

// Round 14
// 54.013 us; speedup vs baseline: 1.0897x; 1.0897x over previous
//
#include <hip/hip_runtime.h>
#include <math.h>

namespace {
constexpr int N_ = 2048;
constexpr int D_ = 128;
constexpr int K_ = 8;
constexpr int M_ = 64;
constexpr float JIT = 1e-5f;
constexpr float L2E = 1.4426950408889634f;
constexpr float LN2 = 0.6931471805599453f;

// bar ints at ws[0..32), zeroed by the memset dispatch each launch:
//   bar[0..8)  : prep chunk counters (target 1 each; prep block b -> bar[b])
//   bar[8..24) : psi2 slice counters (slice s -> bar[8+s], target 16)
//   bar[24]    : p1y arrivals (target 8)
//   bar[25]    : Kuu sweep done (target 1)
//   bar[26]    : YY/KL done (target 1)
//   bar[27]    : reduced-psi2 slice arrivals (target 16)
constexpr int OFF_ARR2 = 32;                    // N*16 : per-n [a[8], ib2s[8]]
constexpr int OFF_C2   = OFF_ARR2 + N_ * 16;    // N
constexpr int OFF_P2P  = OFF_C2 + N_;           // 16*4096 psi2 partials
constexpr int OFF_P1Y  = OFF_P2P + 16 * 4096;   // 8*64
constexpr int OFF_PSI2 = OFF_P1Y + 512;         // 4096 reduced psi2 (left folded)
constexpr int OFF_KUI  = OFF_PSI2 + 4096;       // 4096 : -Kuu^{-1}
constexpr int OFF_SC   = OFF_KUI + 4096;        // 3 : YY, KL, log2det(Kuu)
}

struct F8 { float f[8]; };

// ---- barrier primitives (proven r9-r13) ------------------------------------
__device__ __forceinline__ void bar_arrive(int* c) {
  __syncthreads();
  if (threadIdx.x == 0) { __threadfence(); atomicAdd(c, 1); }
}
template <int SLP>
__device__ __forceinline__ void bar_wait(int* c, int target) {
  if (threadIdx.x == 0) {
    while (__hip_atomic_load(c, __ATOMIC_RELAXED, __HIP_MEMORY_SCOPE_AGENT) < target)
      __builtin_amdgcn_s_sleep(SLP);
    __threadfence();
  }
  __syncthreads();
}

// ---------------------------------------------------------------------------
// 4-wave software-pipelined 2x2-block symmetric sweep (verified r12/r13).
//   reg[r] = A[16*wave + r][lane]  ->  (-A^{-1})[16*wave + r][lane]
// Returns log2(det A), identical in every thread.
// ---------------------------------------------------------------------------
__device__ __forceinline__ float sweep2x2_pipe(
    float* reg, float (*rowbuf)[2][M_], int wave, int lane) {
  if (wave == 0) {
    rowbuf[0][0][lane] = reg[0];
    rowbuf[0][1][lane] = reg[1];
  }
  __syncthreads();
  float ld = 0.f;
#pragma unroll
  for (int s = 0; s < 32; ++s) {
    const int p = 2 * s;
    const int par = s & 1;
    float* rbA = rowbuf[par][0];
    float* rbB = rowbuf[par][1];
    const int own_s  = s >> 3;
    const int own_s1 = (s + 1) >> 3;
    const int rp  = p & 15;
    const int rp2 = (p + 2) & 15;

    const float P00 = rbA[p];
    const float P01 = rbA[p + 1];
    const float P11 = rbB[p + 1];
    const float a0  = rbA[lane];
    const float a1  = rbB[lane];
    const float det = fmaf(P00, P11, -P01 * P01);
    const float idet = __builtin_amdgcn_rcpf(det);
    ld += __log2f(det);
    const float Pi00 =  P11 * idet;
    const float Pi01 = -P01 * idet;
    const float Pi11 =  P00 * idet;

    const bool isp = (lane == p), isq = (lane == p + 1);
    const float w0 = isp ? Pi00 : (isq ? Pi01 : fmaf(Pi00, a0, Pi01 * a1));
    const float w1 = isp ? Pi01 : (isq ? Pi11 : fmaf(Pi01, a0, Pi11 * a1));
    const float t0 = isp ? (1.f - w0) : (isq ? -w0 : w0);
    const float t1 = isq ? (1.f - w1) : (isp ? -w1 : w1);
    const float f0 = (isp || isq) ? -w0 : w0;
    const float f1 = (isp || isq) ? -w1 : w1;

    if (s < 31 && wave == own_s1) {
      const float e0 = fmaf(-t1, rbB[p + 2], fmaf(-t0, rbA[p + 2], reg[rp2]));
      const float e1 = fmaf(-t1, rbB[p + 3], fmaf(-t0, rbA[p + 3], reg[rp2 + 1]));
      rowbuf[par ^ 1][0][lane] = e0;
      rowbuf[par ^ 1][1][lane] = e1;
    }

    const float4* rAq = reinterpret_cast<const float4*>(rbA + 16 * wave);
    const float4* rBq = reinterpret_cast<const float4*>(rbB + 16 * wave);
#pragma unroll
    for (int q = 0; q < 4; q++) {
      const float4 va = rAq[q], vb = rBq[q];
      reg[4 * q + 0] = fmaf(-t1, vb.x, fmaf(-t0, va.x, reg[4 * q + 0]));
      reg[4 * q + 1] = fmaf(-t1, vb.y, fmaf(-t0, va.y, reg[4 * q + 1]));
      reg[4 * q + 2] = fmaf(-t1, vb.z, fmaf(-t0, va.z, reg[4 * q + 2]));
      reg[4 * q + 3] = fmaf(-t1, vb.w, fmaf(-t0, va.w, reg[4 * q + 3]));
    }
    if (wave == own_s) { reg[rp] = f0; reg[rp + 1] = f1; }
    __syncthreads();
  }
  return ld;
}

// ---------------------------------------------------------------------------
// Fused mega kernel, 267 blocks x 256 threads.
//   b 0..7  : prep chunk b -> ws(ARR2,C2) -> arrive bar[b]; then fused p1y
//             (LDS-resident, r2/r13-verified) -> arrive bar[24].
//   b 8     : Kuu^{-1} pipelined sweep -> ws(KUI, SC2) -> arrive bar[25].
//   b 9     : YY + KL -> ws(SC0, SC1) -> arrive bar[26].
//   b 10    : tail. base preload -> wait bar[27]=16 -> reg=base+p2v ->
//             sweep -> wait bar[25]: trace -> wait bar[24]: quad ->
//             wait bar[26]: combine -> out[0].
//   b 11+   : worker w=b-11: wait bar[w>>5]=1 -> stage chunk w>>4 -> psi2
//             slice w&15 -> arrive bar[8+(w&15)].
//             w<16: also reducer: wait bar[8+w]=16 -> reduce slice w ->
//             arrive bar[27].
// ---------------------------------------------------------------------------
__global__ __launch_bounds__(256) void vdmgp_mega(
    const float* __restrict__ X, const float* __restrict__ Y,
    const float* __restrict__ qmu, const float* __restrict__ qcov,
    const float* __restrict__ Z,
    const float* __restrict__ sfp, const float* __restrict__ nvp,
    float* __restrict__ ws, float* __restrict__ out) {
  __shared__ __align__(16) float pool[6656];

  int* bar = (int*)ws;
  const int tid = threadIdx.x;
  const int b = blockIdx.x;
  const float sf = sfp[0];

  if (b < 8) {
    // ---- prep chunk b + fused p1y (r13-verified block) ----
    float* smu = pool;            // [d][k], 1024
    float* scov = pool + 1024;    // 1024
    float* sa1 = pool + 2048;     // 256*16
    float* scy = pool + 6144;     // 256
    float* red = pool + 6400;     // 256

    for (int idx = tid; idx < K_ * D_; idx += 256) {
      int k = idx >> 7, d = idx & 127;
      smu[d * K_ + k]  = qmu[idx];
      scov[d * K_ + k] = qcov[idx];
    }
    __syncthreads();

    const int n = b * 256 + tid;
    float a[K_], s2[K_];
#pragma unroll
    for (int k = 0; k < K_; k++) { a[k] = 0.f; s2[k] = 0.f; }

    const float4* xrow = reinterpret_cast<const float4*>(X + n * D_);
    for (int dq = 0; dq < D_ / 4; dq++) {
      float4 xv = xrow[dq];
      float xs[4] = {xv.x, xv.y, xv.z, xv.w};
#pragma unroll
      for (int t = 0; t < 4; t++) {
        const int d = dq * 4 + t;
        const float x = xs[t];
        const float xx = x * x;
        F8 mu = *reinterpret_cast<const F8*>(&smu[d * K_]);
        F8 cv = *reinterpret_cast<const F8*>(&scov[d * K_]);
#pragma unroll
        for (int k = 0; k < K_; k++) {
          a[k]  = fmaf(mu.f[k], x, a[k]);
          s2[k] = fmaf(cv.f[k], xx, s2[k]);
        }
      }
    }

    float4 w2[4];
    float prod2 = 1.f, prod1 = 1.f;
#pragma unroll
    for (int k = 0; k < K_; k++) {
      const float b2 = 2.f * s2[k] + 1.f;
      const float b1 = 1.f + s2[k];
      reinterpret_cast<float*>(w2)[k]     = a[k];
      reinterpret_cast<float*>(w2)[8 + k] = L2E / b2;
      sa1[tid * 16 + k]     = a[k];
      sa1[tid * 16 + 8 + k] = 0.5f * L2E / b1;
      prod2 *= rsqrtf(b2);
      prod1 *= rsqrtf(b1);
    }
    float4* a2q = reinterpret_cast<float4*>(ws + OFF_ARR2 + n * 16);
#pragma unroll
    for (int e = 0; e < 4; e++) a2q[e] = w2[e];
    (ws + OFF_C2)[n] = prod2;
    scy[tid] = prod1 * Y[n];

    bar_arrive(&bar[b]);              // unblock workers for chunks 2b, 2b+1

    // p1y over this block's 256 n's (LDS-resident; off workers' path)
    const int m = tid & 63;
    const int stripe = tid >> 6;
    float zm[K_];
#pragma unroll
    for (int k = 0; k < K_; k++) zm[k] = Z[m * K_ + k];
    float acc = 0.f;
    for (int t = 0; t < 64; t++) {
      const int nl = stripe * 64 + t;
      const F8 av = *reinterpret_cast<const F8*>(&sa1[nl * 16]);
      const F8 ib = *reinterpret_cast<const F8*>(&sa1[nl * 16 + 8]);
      float s = 0.f;
#pragma unroll
      for (int k = 0; k < K_; k++) {
        const float d = av.f[k] - zm[k];
        s = fmaf(d * d, ib.f[k], s);
      }
      acc = fmaf(scy[nl], exp2f(-s), acc);
    }
    red[tid] = acc;
    __syncthreads();
    if (tid < 64)
      (ws + OFF_P1Y)[b * 64 + tid] =
          red[tid] + red[64 + tid] + red[128 + tid] + red[192 + tid];
    bar_arrive(&bar[24]);
    return;
  }

  if (b == 8) {
    // ---- Kuu^{-1} sweep (r12-verified) ----
    float (*zl)[9] = reinterpret_cast<float(*)[9]>(pool);              // 576
    float (*rowbuf)[2][M_] = reinterpret_cast<float(*)[2][M_]>(pool + 576);
    for (int idx = tid; idx < M_ * K_; idx += 256) zl[idx >> 3][idx & 7] = Z[idx];
    __syncthreads();
    const int lane = tid & 63;
    const int wave = tid >> 6;
    float zj[K_];
#pragma unroll
    for (int k = 0; k < K_; k++) zj[k] = zl[lane][k];
    float reg[16];
#pragma unroll
    for (int r = 0; r < 16; r++) {
      const int gi = 16 * wave + r;
      float sq = 0.f;
#pragma unroll
      for (int k = 0; k < K_; k++) { const float dd = zl[gi][k] - zj[k]; sq = fmaf(dd, dd, sq); }
      reg[r] = exp2f(-0.5f * L2E * sq) + ((gi == lane) ? JIT : 0.f);
    }
    const float ld1 = sweep2x2_pipe(reg, rowbuf, wave, lane);
#pragma unroll
    for (int r = 0; r < 16; r++)
      ws[OFF_KUI + (16 * wave + r) * 64 + lane] = reg[r];   // -Kuu^{-1}
    if (tid == 0) ws[OFF_SC + 2] = LN2 * ld1;
    bar_arrive(&bar[25]);
    return;
  }

  if (b == 9) {
    // ---- YY + KL ----
    const int lane = tid & 63;
    const int wave = tid >> 6;
    if (wave == 0) {
      float yy = 0.f;
#pragma unroll
      for (int t = 0; t < 32; t++) {
        const float y = Y[t * 64 + lane];
        yy = fmaf(y, y, yy);
      }
#pragma unroll
      for (int off = 32; off > 0; off >>= 1) yy += __shfl_down(yy, off, 64);
      if (lane == 0) ws[OFF_SC + 0] = yy;
    } else if (wave == 1) {
      const int k = lane >> 3;
      const int d0 = (lane & 7) * 16;
      float slog = 0.f, srow = 0.f;
#pragma unroll
      for (int t = 0; t < 16; t++) {
        const float qc = qcov[k * D_ + d0 + t];
        const float qm = qmu[k * D_ + d0 + t];
        slog += logf(qc);
        srow += qc + qm * qm;
      }
#pragma unroll
      for (int off = 4; off > 0; off >>= 1) {
        slog += __shfl_down(slog, off, 8);
        srow += __shfl_down(srow, off, 8);
      }
      float klr = ((lane & 7) == 0)
          ? (slog - (float)D_ * logf(srow) + (float)D_ * logf((float)D_)) : 0.f;
      klr += __shfl_down(klr, 32, 64);
      klr += __shfl_down(klr, 16, 64);
      klr += __shfl_down(klr, 8, 64);
      if (lane == 0) ws[OFF_SC + 1] = klr;
    }
    bar_arrive(&bar[26]);
    return;
  }

  if (b >= 11) {
    // ---- worker w: psi2 slice (r12-verified), prep-gated ----
    const int w = b - 11;
    const int chunk = w >> 4;
    const int slice = w & 15;
    float* sa = pool;           // 128*16
    float* sc = pool + 2048;    // 128

    bar_wait<8>(&bar[w >> 5], 1);    // prep block (chunk>>1) done

    const int nbase = chunk * 128;
    {
      const float4* src = reinterpret_cast<const float4*>(ws + OFF_ARR2 + nbase * 16);
      float4* dst = reinterpret_cast<float4*>(sa);
      for (int idx = tid; idx < 512; idx += 256) dst[idx] = src[idx];
      if (tid < 128) sc[tid] = (ws + OFF_C2)[nbase + tid];
    }
    __syncthreads();

    const int pair = slice * 256 + tid;
    const int i = pair >> 6, j = pair & 63;
    float zb[K_];
#pragma unroll
    for (int k = 0; k < K_; k++) zb[k] = 0.5f * (Z[i * K_ + k] + Z[j * K_ + k]);

    float acc = 0.f;
    for (int nl = 0; nl < 128; nl += 4) {
      F8 av0 = *reinterpret_cast<const F8*>(&sa[(nl + 0) * 16]);
      F8 ib0 = *reinterpret_cast<const F8*>(&sa[(nl + 0) * 16 + 8]);
      F8 av1 = *reinterpret_cast<const F8*>(&sa[(nl + 1) * 16]);
      F8 ib1 = *reinterpret_cast<const F8*>(&sa[(nl + 1) * 16 + 8]);
      F8 av2 = *reinterpret_cast<const F8*>(&sa[(nl + 2) * 16]);
      F8 ib2 = *reinterpret_cast<const F8*>(&sa[(nl + 2) * 16 + 8]);
      F8 av3 = *reinterpret_cast<const F8*>(&sa[(nl + 3) * 16]);
      F8 ib3 = *reinterpret_cast<const F8*>(&sa[(nl + 3) * 16 + 8]);
      float s0 = 0.f, s1 = 0.f, s2 = 0.f, s3 = 0.f;
#pragma unroll
      for (int k = 0; k < K_; k++) {
        const float d0 = av0.f[k] - zb[k]; s0 = fmaf(d0 * d0, ib0.f[k], s0);
        const float d1 = av1.f[k] - zb[k]; s1 = fmaf(d1 * d1, ib1.f[k], s1);
        const float d2 = av2.f[k] - zb[k]; s2 = fmaf(d2 * d2, ib2.f[k], s2);
        const float d3 = av3.f[k] - zb[k]; s3 = fmaf(d3 * d3, ib3.f[k], s3);
      }
      acc = fmaf(sc[nl + 0], exp2f(-s0), acc);
      acc = fmaf(sc[nl + 1], exp2f(-s1), acc);
      acc = fmaf(sc[nl + 2], exp2f(-s2), acc);
      acc = fmaf(sc[nl + 3], exp2f(-s3), acc);
    }
    (ws + OFF_P2P)[chunk * 4096 + pair] = acc;
    bar_arrive(&bar[8 + slice]);

    if (w < 16) {
      // reducer for slice w (r12-verified)
      bar_wait<4>(&bar[8 + w], 16);
      const int p = w * 256 + tid;
      float racc = 0.f;
#pragma unroll
      for (int c = 0; c < 16; c++) racc += ws[OFF_P2P + c * 4096 + p];
      const int ri = p >> 6, rj = p & 63;
      float sq = 0.f;
#pragma unroll
      for (int k = 0; k < K_; k++) {
        const float dd = Z[ri * K_ + k] - Z[rj * K_ + k];
        sq = fmaf(dd, dd, sq);
      }
      ws[OFF_PSI2 + p] = sf * sf * exp2f(-0.25f * L2E * sq) * racc;
      bar_arrive(&bar[27]);
    }
    return;
  }

  // -------- b == 10: tail --------
  float (*zl)[9]         = reinterpret_cast<float(*)[9]>(pool);            // 576
  float (*rowbuf)[2][M_] = reinterpret_cast<float(*)[2][M_]>(pool + 576);  // 256
  float* pysL  = pool + 832;                                               // 64
  float* scalL = pool + 896;                                               // 8
  float* redQ  = pool + 912;                                               // 256
  float* redT  = pool + 1168;                                              // 256

  const int lane = tid & 63;
  const int wave = tid >> 6;
  const float s2v = nvp[0];

  for (int idx = tid; idx < M_ * K_; idx += 256) zl[idx >> 3][idx & 7] = Z[idx];
  __syncthreads();

  // preload A2's Kuu part (independent of all producers)
  float zj[K_];
#pragma unroll
  for (int k = 0; k < K_; k++) zj[k] = zl[lane][k];
  float base[16];
#pragma unroll
  for (int r = 0; r < 16; r++) {
    const int gi = 16 * wave + r;
    float sq = 0.f;
#pragma unroll
    for (int k = 0; k < K_; k++) { const float dd = zl[gi][k] - zj[k]; sq = fmaf(dd, dd, sq); }
    const float jit = (gi == lane) ? JIT : 0.f;
    base[r] = fmaf(s2v, exp2f(-0.5f * L2E * sq) + jit, jit);
  }

  bar_wait<4>(&bar[27], 16);    // reduced psi2 ready

  float reg[16], p2v[16];
#pragma unroll
  for (int r = 0; r < 16; r++) {
    p2v[r] = ws[OFF_PSI2 + (16 * wave + r) * 64 + lane];
    reg[r] = base[r] + p2v[r];
  }

  const float ld2 = sweep2x2_pipe(reg, rowbuf, wave, lane);

  bar_wait<4>(&bar[25], 1);     // Kuu^{-1} ready (long done)
  float sT = 0.f;
#pragma unroll
  for (int r = 0; r < 16; r++)
    sT = fmaf(ws[OFF_KUI + (16 * wave + r) * 64 + lane], p2v[r], sT);
  redT[tid] = sT;

  bar_wait<4>(&bar[24], 8);     // p1y ready (long done)
  if (tid < M_) {
    float s = 0.f;
#pragma unroll
    for (int c = 0; c < 8; c++) s += ws[OFF_P1Y + c * M_ + tid];
    pysL[tid] = sf * s;
  }
  __syncthreads();

  float sQ = 0.f;
#pragma unroll
  for (int r = 0; r < 16; r++) sQ = fmaf(reg[r], pysL[16 * wave + r], sQ);
  redQ[tid] = sQ;
  __syncthreads();

  if (wave == 0) {
    float c = redQ[lane] + redQ[64 + lane] + redQ[128 + lane] + redQ[192 + lane];
    float q = c * pysL[lane];
#pragma unroll
    for (int off = 32; off > 0; off >>= 1) q += __shfl_down(q, off, 64);
    if (lane == 0) scalL[7] = -q;    // quad
  } else if (wave == 1) {
    float s = redT[lane] + redT[64 + lane] + redT[128 + lane] + redT[192 + lane];
#pragma unroll
    for (int off = 32; off > 0; off >>= 1) s += __shfl_down(s, off, 64);
    if (lane == 0) scalL[5] = -s;    // trace
  }
  __syncthreads();

  bar_wait<4>(&bar[26], 1);     // YY/KL ready (long done)
  if (tid == 0) {
    const float YY  = ws[OFF_SC + 0];
    const float KL  = ws[OFF_SC + 1];
    const float ld1 = ws[OFF_SC + 2];
    const float tr = scalL[5], quad = scalL[7];
    const float inv = 1.0f / s2v;
    const float F1 = -(float)N_ * 1.8378770664093453f
                   - (float)(N_ - M_) * logf(s2v)
                   + (ld1 - LN2 * ld2)
                   - YY * inv
                   + quad * inv
                   - (float)N_ * sf * sf * inv
                   + tr * inv;
    out[0] = 0.5f * (F1 + KL);
  }
}

extern "C" void kernel_launch(void* const* d_in, const int* in_sizes, int n_in,
                              void* d_out, int out_size, void* d_ws, size_t ws_size,
                              hipStream_t stream) {
  const float* X    = (const float*)d_in[0];
  const float* Y    = (const float*)d_in[1];
  const float* qmu  = (const float*)d_in[2];
  const float* qcov = (const float*)d_in[3];
  const float* Z    = (const float*)d_in[4];
  const float* sfp  = (const float*)d_in[5];
  const float* nvp  = (const float*)d_in[6];
  float* ws  = (float*)d_ws;
  float* out = (float*)d_out;

  hipMemsetAsync(d_ws, 0, 128, stream);   // zero the 32 barrier ints
  vdmgp_mega<<<267, 256, 0, stream>>>(X, Y, qmu, qcov, Z, sfp, nvp, ws, out);
}

// Round 15
// 53.230 us; speedup vs baseline: 1.1057x; 1.0147x over previous
//
#include <hip/hip_runtime.h>
#include <math.h>

namespace {
constexpr int N_ = 2048;
constexpr int D_ = 128;
constexpr int K_ = 8;
constexpr int M_ = 64;
constexpr float JIT = 1e-5f;
constexpr float L2E = 1.4426950408889634f;
constexpr float LN2 = 0.6931471805599453f;

// ws float offsets. bar region: 32 ints at ws[0..32), zeroed by K1 block 0.
//   bar[s], s in [0,16) : psi2 slice counters (worker t -> bar[t&15], target 16)
//   bar[16]             : p1y arrivals (target 8)
constexpr int OFF_ARR2 = 32;                    // N*16 : per-n [a[8], ib2s[8]]
constexpr int OFF_C2   = OFF_ARR2 + N_ * 16;    // N
constexpr int OFF_ARR1 = OFF_C2 + N_;           // N*16 : per-n [a[8], ib1s[8]]
constexpr int OFF_CY   = OFF_ARR1 + N_ * 16;    // N
constexpr int OFF_P2P  = OFF_CY + N_;           // 16*4096 psi2 partials
constexpr int OFF_P1Y  = OFF_P2P + 16 * 4096;   // 8*64
constexpr int OFF_KUI  = OFF_P1Y + 512;         // 4096 : -Kuu^{-1}
constexpr int OFF_SC   = OFF_KUI + 4096;        // 3 : YY, KL, log2det(Kuu)
}

struct F8 { float f[8]; };

// ---- barrier primitives ----------------------------------------------------
__device__ __forceinline__ void bar_arrive(int* c) {
  __syncthreads();
  if (threadIdx.x == 0) { __threadfence(); atomicAdd(c, 1); }
}
template <int SLP>
__device__ __forceinline__ void bar_wait(int* c, int target) {
  if (threadIdx.x == 0) {
    while (__hip_atomic_load(c, __ATOMIC_RELAXED, __HIP_MEMORY_SCOPE_AGENT) < target)
      __builtin_amdgcn_s_sleep(SLP);
    __threadfence();
  }
  __syncthreads();
}

// ---------------------------------------------------------------------------
// 4-wave software-pipelined 2x2-block symmetric sweep (verified r12/r13).
//   reg[r] = A[16*wave + r][lane]  ->  (-A^{-1})[16*wave + r][lane]
// Returns log2(det A), identical in every thread.
// ---------------------------------------------------------------------------
__device__ __forceinline__ float sweep2x2_pipe(
    float* reg, float (*rowbuf)[2][M_], int wave, int lane) {
  if (wave == 0) {
    rowbuf[0][0][lane] = reg[0];
    rowbuf[0][1][lane] = reg[1];
  }
  __syncthreads();
  float ld = 0.f;
#pragma unroll
  for (int s = 0; s < 32; ++s) {
    const int p = 2 * s;
    const int par = s & 1;
    float* rbA = rowbuf[par][0];
    float* rbB = rowbuf[par][1];
    const int own_s  = s >> 3;
    const int own_s1 = (s + 1) >> 3;
    const int rp  = p & 15;
    const int rp2 = (p + 2) & 15;

    const float P00 = rbA[p];
    const float P01 = rbA[p + 1];
    const float P11 = rbB[p + 1];
    const float a0  = rbA[lane];
    const float a1  = rbB[lane];
    const float det = fmaf(P00, P11, -P01 * P01);
    const float idet = __builtin_amdgcn_rcpf(det);
    ld += __log2f(det);
    const float Pi00 =  P11 * idet;
    const float Pi01 = -P01 * idet;
    const float Pi11 =  P00 * idet;

    const bool isp = (lane == p), isq = (lane == p + 1);
    const float w0 = isp ? Pi00 : (isq ? Pi01 : fmaf(Pi00, a0, Pi01 * a1));
    const float w1 = isp ? Pi01 : (isq ? Pi11 : fmaf(Pi01, a0, Pi11 * a1));
    const float t0 = isp ? (1.f - w0) : (isq ? -w0 : w0);
    const float t1 = isq ? (1.f - w1) : (isp ? -w1 : w1);
    const float f0 = (isp || isq) ? -w0 : w0;
    const float f1 = (isp || isq) ? -w1 : w1;

    if (s < 31 && wave == own_s1) {
      const float e0 = fmaf(-t1, rbB[p + 2], fmaf(-t0, rbA[p + 2], reg[rp2]));
      const float e1 = fmaf(-t1, rbB[p + 3], fmaf(-t0, rbA[p + 3], reg[rp2 + 1]));
      rowbuf[par ^ 1][0][lane] = e0;
      rowbuf[par ^ 1][1][lane] = e1;
    }

    const float4* rAq = reinterpret_cast<const float4*>(rbA + 16 * wave);
    const float4* rBq = reinterpret_cast<const float4*>(rbB + 16 * wave);
#pragma unroll
    for (int q = 0; q < 4; q++) {
      const float4 va = rAq[q], vb = rBq[q];
      reg[4 * q + 0] = fmaf(-t1, vb.x, fmaf(-t0, va.x, reg[4 * q + 0]));
      reg[4 * q + 1] = fmaf(-t1, vb.y, fmaf(-t0, va.y, reg[4 * q + 1]));
      reg[4 * q + 2] = fmaf(-t1, vb.z, fmaf(-t0, va.z, reg[4 * q + 2]));
      reg[4 * q + 3] = fmaf(-t1, vb.w, fmaf(-t0, va.w, reg[4 * q + 3]));
    }
    if (wave == own_s) { reg[rp] = f0; reg[rp + 1] = f1; }
    __syncthreads();
  }
  return ld;
}

// ---------------------------------------------------------------------------
// K1: 10 blocks (r12-verified). b<8: prep. b==8: Kuu^{-1} sweep. b==9: YY+KL.
// Block 0 zeroes the 32 barrier ints (K2 is stream-ordered after K1).
// ---------------------------------------------------------------------------
__global__ __launch_bounds__(256) void vdmgp_k1(
    const float* __restrict__ X, const float* __restrict__ Y,
    const float* __restrict__ qmu, const float* __restrict__ qcov,
    const float* __restrict__ Z, float* __restrict__ ws) {
  __shared__ float smu[D_ * K_];   // [d][k]
  __shared__ float scov[D_ * K_];
  __shared__ float zl[M_][9];
  __shared__ __align__(16) float rowbuf[2][2][M_];
  const int tid = threadIdx.x;
  const int b = blockIdx.x;

  if (b == 0 && tid < 32) ((int*)ws)[tid] = 0;

  if (b == 8) {
    for (int idx = tid; idx < M_ * K_; idx += 256) zl[idx >> 3][idx & 7] = Z[idx];
    __syncthreads();
    const int lane = tid & 63;
    const int wave = tid >> 6;
    float zj[K_];
#pragma unroll
    for (int k = 0; k < K_; k++) zj[k] = zl[lane][k];
    float reg[16];
#pragma unroll
    for (int r = 0; r < 16; r++) {
      const int gi = 16 * wave + r;
      float sq = 0.f;
#pragma unroll
      for (int k = 0; k < K_; k++) { const float dd = zl[gi][k] - zj[k]; sq = fmaf(dd, dd, sq); }
      reg[r] = exp2f(-0.5f * L2E * sq) + ((gi == lane) ? JIT : 0.f);
    }
    const float ld1 = sweep2x2_pipe(reg, rowbuf, wave, lane);
#pragma unroll
    for (int r = 0; r < 16; r++)
      ws[OFF_KUI + (16 * wave + r) * 64 + lane] = reg[r];   // -Kuu^{-1}
    if (tid == 0) ws[OFF_SC + 2] = LN2 * ld1;
    return;
  }

  if (b == 9) {
    const int lane = tid & 63;
    const int wave = tid >> 6;
    if (wave == 0) {
      float yy = 0.f;
#pragma unroll
      for (int t = 0; t < 32; t++) {
        const float y = Y[t * 64 + lane];
        yy = fmaf(y, y, yy);
      }
#pragma unroll
      for (int off = 32; off > 0; off >>= 1) yy += __shfl_down(yy, off, 64);
      if (lane == 0) ws[OFF_SC + 0] = yy;
    } else if (wave == 1) {
      const int k = lane >> 3;
      const int d0 = (lane & 7) * 16;
      float slog = 0.f, srow = 0.f;
#pragma unroll
      for (int t = 0; t < 16; t++) {
        const float qc = qcov[k * D_ + d0 + t];
        const float qm = qmu[k * D_ + d0 + t];
        slog += logf(qc);
        srow += qc + qm * qm;
      }
#pragma unroll
      for (int off = 4; off > 0; off >>= 1) {
        slog += __shfl_down(slog, off, 8);
        srow += __shfl_down(srow, off, 8);
      }
      float klr = ((lane & 7) == 0)
          ? (slog - (float)D_ * logf(srow) + (float)D_ * logf((float)D_)) : 0.f;
      klr += __shfl_down(klr, 32, 64);
      klr += __shfl_down(klr, 16, 64);
      klr += __shfl_down(klr, 8, 64);
      if (lane == 0) ws[OFF_SC + 1] = klr;
    }
    return;
  }

  // prep: one n per thread (r12-verified)
  for (int idx = tid; idx < K_ * D_; idx += 256) {
    int k = idx >> 7, d = idx & 127;
    smu[d * K_ + k]  = qmu[idx];
    scov[d * K_ + k] = qcov[idx];
  }
  __syncthreads();

  const int n = b * 256 + tid;
  float a[K_], s2[K_];
#pragma unroll
  for (int k = 0; k < K_; k++) { a[k] = 0.f; s2[k] = 0.f; }

  const float4* xrow = reinterpret_cast<const float4*>(X + n * D_);
#pragma unroll 2
  for (int dq = 0; dq < D_ / 4; dq++) {
    float4 xv = xrow[dq];
    float xs[4] = {xv.x, xv.y, xv.z, xv.w};
#pragma unroll
    for (int t = 0; t < 4; t++) {
      const int d = dq * 4 + t;
      const float x = xs[t];
      const float xx = x * x;
      F8 mu = *reinterpret_cast<const F8*>(&smu[d * K_]);
      F8 cv = *reinterpret_cast<const F8*>(&scov[d * K_]);
#pragma unroll
      for (int k = 0; k < K_; k++) {
        a[k]  = fmaf(mu.f[k], x, a[k]);
        s2[k] = fmaf(cv.f[k], xx, s2[k]);
      }
    }
  }

  float4 w2[4], w1[4];
  float prod2 = 1.f, prod1 = 1.f;
#pragma unroll
  for (int k = 0; k < K_; k++) {
    const float b2 = 2.f * s2[k] + 1.f;
    const float b1 = 1.f + s2[k];
    reinterpret_cast<float*>(w2)[k]     = a[k];
    reinterpret_cast<float*>(w2)[8 + k] = L2E / b2;
    reinterpret_cast<float*>(w1)[k]     = a[k];
    reinterpret_cast<float*>(w1)[8 + k] = 0.5f * L2E / b1;
    prod2 *= rsqrtf(b2);
    prod1 *= rsqrtf(b1);
  }
  float4* a2q = reinterpret_cast<float4*>(ws + OFF_ARR2 + n * 16);
  float4* a1q = reinterpret_cast<float4*>(ws + OFF_ARR1 + n * 16);
#pragma unroll
  for (int e = 0; e < 4; e++) { a2q[e] = w2[e]; a1q[e] = w1[e]; }
  (ws + OFF_C2)[n] = prod2;
  (ws + OFF_CY)[n] = prod1 * Y[n];
}

// ---------------------------------------------------------------------------
// K2: 257 blocks (r12 structure, reducer hop removed).
//   b==0        : tail. Preload zl/base/left/kui (regs) -> wait 16 slice
//                 counters -> reduce own slice (fold left) + trace partial ->
//                 pipelined A2 sweep -> wait p1y -> quad -> combine -> out.
//   b>=1, t=b-1 : psi2 task (chunk t>>4, pairblk t&15) -> arrive bar[t&15].
//                 16<=t<24 : then Psi1^T Y chunk (t-16) -> arrive bar[16].
// ---------------------------------------------------------------------------
__global__ __launch_bounds__(256) void vdmgp_k2(
    const float* __restrict__ Z,
    const float* __restrict__ sfp, const float* __restrict__ nvp,
    float* __restrict__ ws, float* __restrict__ out) {
  __shared__ __align__(16) float pool[4864];

  int* bar = (int*)ws;
  const int tid = threadIdx.x;
  const int b = blockIdx.x;
  const float sf = sfp[0];

  if (b > 0) {
    const int t = b - 1;
    // -------- psi2 task (r12-verified x4-unrolled) --------
    {
      float* sa = pool;           // 128*16
      float* sc = pool + 2048;    // 128
      const int chunk = t >> 4;
      const int nbase = chunk * 128;
      const float4* src = reinterpret_cast<const float4*>(ws + OFF_ARR2 + nbase * 16);
      float4* dst = reinterpret_cast<float4*>(sa);
      for (int idx = tid; idx < 512; idx += 256) dst[idx] = src[idx];
      if (tid < 128) sc[tid] = (ws + OFF_C2)[nbase + tid];
      __syncthreads();

      const int pair = (t & 15) * 256 + tid;
      const int i = pair >> 6, j = pair & 63;
      float zb[K_];
#pragma unroll
      for (int k = 0; k < K_; k++) zb[k] = 0.5f * (Z[i * K_ + k] + Z[j * K_ + k]);

      float acc = 0.f;
      for (int nl = 0; nl < 128; nl += 4) {
        F8 av0 = *reinterpret_cast<const F8*>(&sa[(nl + 0) * 16]);
        F8 ib0 = *reinterpret_cast<const F8*>(&sa[(nl + 0) * 16 + 8]);
        F8 av1 = *reinterpret_cast<const F8*>(&sa[(nl + 1) * 16]);
        F8 ib1 = *reinterpret_cast<const F8*>(&sa[(nl + 1) * 16 + 8]);
        F8 av2 = *reinterpret_cast<const F8*>(&sa[(nl + 2) * 16]);
        F8 ib2 = *reinterpret_cast<const F8*>(&sa[(nl + 2) * 16 + 8]);
        F8 av3 = *reinterpret_cast<const F8*>(&sa[(nl + 3) * 16]);
        F8 ib3 = *reinterpret_cast<const F8*>(&sa[(nl + 3) * 16 + 8]);
        float s0 = 0.f, s1 = 0.f, s2 = 0.f, s3 = 0.f;
#pragma unroll
        for (int k = 0; k < K_; k++) {
          const float d0 = av0.f[k] - zb[k]; s0 = fmaf(d0 * d0, ib0.f[k], s0);
          const float d1 = av1.f[k] - zb[k]; s1 = fmaf(d1 * d1, ib1.f[k], s1);
          const float d2 = av2.f[k] - zb[k]; s2 = fmaf(d2 * d2, ib2.f[k], s2);
          const float d3 = av3.f[k] - zb[k]; s3 = fmaf(d3 * d3, ib3.f[k], s3);
        }
        acc = fmaf(sc[nl + 0], exp2f(-s0), acc);
        acc = fmaf(sc[nl + 1], exp2f(-s1), acc);
        acc = fmaf(sc[nl + 2], exp2f(-s2), acc);
        acc = fmaf(sc[nl + 3], exp2f(-s3), acc);
      }
      (ws + OFF_P2P)[chunk * 4096 + (t & 15) * 256 + tid] = acc;
    }
    bar_arrive(&bar[t & 15]);

    if (t >= 16 && t < 24) {
      // -------- Psi1^T Y chunk (t-16), r12-verified --------
      float* sa1 = pool;          // 256*16
      float* scy = pool + 4096;   // 256
      float* red = pool + 4352;   // 256
      const int chunk = t - 16;
      const int nbase = chunk * 256;
      const float4* src = reinterpret_cast<const float4*>(ws + OFF_ARR1 + nbase * 16);
      float4* dst = reinterpret_cast<float4*>(sa1);
#pragma unroll
      for (int r = 0; r < 4; r++) dst[r * 256 + tid] = src[r * 256 + tid];
      scy[tid] = (ws + OFF_CY)[nbase + tid];
      __syncthreads();

      const int m = tid & 63;
      const int stripe = tid >> 6;
      float zm[K_];
#pragma unroll
      for (int k = 0; k < K_; k++) zm[k] = Z[m * K_ + k];

      float acc = 0.f;
      for (int u = 0; u < 64; u++) {
        const int nl = stripe * 64 + u;
        const F8 av = *reinterpret_cast<const F8*>(&sa1[nl * 16]);
        const F8 ib = *reinterpret_cast<const F8*>(&sa1[nl * 16 + 8]);
        float s = 0.f;
#pragma unroll
        for (int k = 0; k < K_; k++) {
          const float d = av.f[k] - zm[k];
          s = fmaf(d * d, ib.f[k], s);
        }
        acc = fmaf(scy[nl], exp2f(-s), acc);
      }
      red[tid] = acc;
      __syncthreads();
      if (tid < 64)
        (ws + OFF_P1Y)[chunk * 64 + tid] =
            red[tid] + red[64 + tid] + red[128 + tid] + red[192 + tid];
      bar_arrive(&bar[16]);
    }
    return;
  }

  // -------- b == 0: tail (r13-verified tail-reduce + r12 wait-split) --------
  float (*zl)[9]         = reinterpret_cast<float(*)[9]>(pool);            // 576
  float (*rowbuf)[2][M_] = reinterpret_cast<float(*)[2][M_]>(pool + 576);  // 256
  float* pysL  = pool + 832;                                               // 64
  float* scalL = pool + 896;                                               // 8
  float* redQ  = pool + 912;                                               // 256
  float* redT  = pool + 1168;                                              // 256

  const int lane = tid & 63;
  const int wave = tid >> 6;
  const float s2v = nvp[0];
  const float sf2 = sf * sf;

  for (int idx = tid; idx < M_ * K_; idx += 256) zl[idx >> 3][idx & 7] = Z[idx];
  __syncthreads();

  // preload: one exp2 gives both Kuu (e^2) and left (sf^2 * e); kui cols
  float zj[K_];
#pragma unroll
  for (int k = 0; k < K_; k++) zj[k] = zl[lane][k];
  float base[16], leftf[16], kui16[16];
#pragma unroll
  for (int r = 0; r < 16; r++) {
    const int gi = 16 * wave + r;
    float sq = 0.f;
#pragma unroll
    for (int k = 0; k < K_; k++) { const float dd = zl[gi][k] - zj[k]; sq = fmaf(dd, dd, sq); }
    const float e = exp2f(-0.25f * L2E * sq);
    const float jit = (gi == lane) ? JIT : 0.f;
    base[r]  = fmaf(s2v, e * e + jit, jit);
    leftf[r] = sf2 * e;
    kui16[r] = ws[OFF_KUI + gi * 64 + lane];
  }

#pragma unroll
  for (int g = 0; g < 16; g++) bar_wait<2>(&bar[g], 16);

  // reduce own slice of partials, fold left; build A2 rows + trace partial
  float reg[16];
  float sT = 0.f;
#pragma unroll
  for (int r = 0; r < 16; r++) {
    const int pidx = (16 * wave + r) * 64 + lane;
    float s = 0.f;
#pragma unroll
    for (int c = 0; c < 16; c++) s += ws[OFF_P2P + c * 4096 + pidx];
    const float p2v = leftf[r] * s;
    reg[r] = base[r] + p2v;
    sT = fmaf(kui16[r], p2v, sT);
  }
  redT[tid] = sT;

  const float ld2 = sweep2x2_pipe(reg, rowbuf, wave, lane);

  bar_wait<2>(&bar[16], 8);     // p1y ready (normally long done)
  if (tid < M_) {
    float s = 0.f;
#pragma unroll
    for (int c = 0; c < 8; c++) s += ws[OFF_P1Y + c * M_ + tid];
    pysL[tid] = sf * s;
  }
  __syncthreads();

  float sQ = 0.f;
#pragma unroll
  for (int r = 0; r < 16; r++) sQ = fmaf(reg[r], pysL[16 * wave + r], sQ);
  redQ[tid] = sQ;
  __syncthreads();

  if (wave == 0) {
    float c = redQ[lane] + redQ[64 + lane] + redQ[128 + lane] + redQ[192 + lane];
    float q = c * pysL[lane];
#pragma unroll
    for (int off = 32; off > 0; off >>= 1) q += __shfl_down(q, off, 64);
    if (lane == 0) scalL[7] = -q;    // quad
  } else if (wave == 1) {
    float s = redT[lane] + redT[64 + lane] + redT[128 + lane] + redT[192 + lane];
#pragma unroll
    for (int off = 32; off > 0; off >>= 1) s += __shfl_down(s, off, 64);
    if (lane == 0) scalL[5] = -s;    // trace
  }
  __syncthreads();

  if (tid == 0) {
    const float YY  = ws[OFF_SC + 0];
    const float KL  = ws[OFF_SC + 1];
    const float ld1 = ws[OFF_SC + 2];
    const float tr = scalL[5], quad = scalL[7];
    const float inv = 1.0f / s2v;
    const float F1 = -(float)N_ * 1.8378770664093453f
                   - (float)(N_ - M_) * logf(s2v)
                   + (ld1 - LN2 * ld2)
                   - YY * inv
                   + quad * inv
                   - (float)N_ * sf2 * inv
                   + tr * inv;
    out[0] = 0.5f * (F1 + KL);
  }
}

extern "C" void kernel_launch(void* const* d_in, const int* in_sizes, int n_in,
                              void* d_out, int out_size, void* d_ws, size_t ws_size,
                              hipStream_t stream) {
  const float* X    = (const float*)d_in[0];
  const float* Y    = (const float*)d_in[1];
  const float* qmu  = (const float*)d_in[2];
  const float* qcov = (const float*)d_in[3];
  const float* Z    = (const float*)d_in[4];
  const float* sfp  = (const float*)d_in[5];
  const float* nvp  = (const float*)d_in[6];
  float* ws  = (float*)d_ws;
  float* out = (float*)d_out;

  vdmgp_k1<<<10, 256, 0, stream>>>(X, Y, qmu, qcov, Z, ws);
  vdmgp_k2<<<257, 256, 0, stream>>>(Z, sfp, nvp, ws, out);
}

// Round 16
// 49.864 us; speedup vs baseline: 1.1804x; 1.0675x over previous
//
#include <hip/hip_runtime.h>
#include <math.h>

namespace {
constexpr int N_ = 2048;
constexpr int D_ = 128;
constexpr int K_ = 8;
constexpr int M_ = 64;
constexpr float JIT = 1e-5f;
constexpr float L2E = 1.4426950408889634f;
constexpr float LN2 = 0.6931471805599453f;

// ws float offsets. bar region: 32 ints at ws[0..32), zeroed by K1 block 0.
//   bar[s], s in [0,16) : per-pair-slice psi2 arrival counters (target 16)
//   bar[16]             : p1y arrivals (target 8)
//   bar[17]             : reduced-psi2 slice arrivals (target 16)
constexpr int OFF_ARR2 = 32;                    // N*16 : per-n [a[8], ib2s[8]]
constexpr int OFF_C2   = OFF_ARR2 + N_ * 16;    // N
constexpr int OFF_ARR1 = OFF_C2 + N_;           // N*16 : per-n [a[8], ib1s[8]]
constexpr int OFF_CY   = OFF_ARR1 + N_ * 16;    // N
constexpr int OFF_P2P  = OFF_CY + N_;           // 16*4096 psi2 partials
constexpr int OFF_P1Y  = OFF_P2P + 16 * 4096;   // 8*64
constexpr int OFF_PSI2 = OFF_P1Y + 512;         // 4096 reduced psi2 (left folded)
constexpr int OFF_KUI  = OFF_PSI2 + 4096;       // 4096 : -Kuu^{-1}
constexpr int OFF_SC   = OFF_KUI + 4096;        // 3 : YY, KL, log2det(Kuu)
}

struct F8 { float f[8]; };

// ---- barrier primitives ----------------------------------------------------
__device__ __forceinline__ void bar_arrive(int* c) {
  __syncthreads();
  if (threadIdx.x == 0) { __threadfence(); atomicAdd(c, 1); }
}
template <int SLP>
__device__ __forceinline__ void bar_wait(int* c, int target) {
  if (threadIdx.x == 0) {
    while (__hip_atomic_load(c, __ATOMIC_RELAXED, __HIP_MEMORY_SCOPE_AGENT) < target)
      __builtin_amdgcn_s_sleep(SLP);
    __threadfence();
  }
  __syncthreads();
}

// ---------------------------------------------------------------------------
// 4-wave software-pipelined 2x2-block symmetric sweep.
//   reg[r] = A[16*wave + r][lane]  ->  (-A^{-1})[16*wave + r][lane]
// Step s's owner-of-next-pivot publishes rows p+2,p+3 (already updated) into
// the opposite parity buffer DURING step s, so step s+1 never waits on a
// fresh ds_write. One __syncthreads per step; parity double-buffer makes the
// WAR safe (all reads of buf[par^1] finished at end-of-(s-1) sync).
// Returns log2(det A), identical in every thread.
// ---------------------------------------------------------------------------
__device__ __forceinline__ float sweep2x2_pipe(
    float* reg, float (*rowbuf)[2][M_], int wave, int lane) {
  if (wave == 0) {                       // prologue: rows 0,1 (original A)
    rowbuf[0][0][lane] = reg[0];
    rowbuf[0][1][lane] = reg[1];
  }
  __syncthreads();
  float ld = 0.f;
#pragma unroll
  for (int s = 0; s < 32; ++s) {
    const int p = 2 * s;
    const int par = s & 1;
    float* rbA = rowbuf[par][0];
    float* rbB = rowbuf[par][1];
    const int own_s  = s >> 3;
    const int own_s1 = (s + 1) >> 3;
    const int rp  = p & 15;
    const int rp2 = (p + 2) & 15;

    const float P00 = rbA[p];
    const float P01 = rbA[p + 1];
    const float P11 = rbB[p + 1];
    const float a0  = rbA[lane];
    const float a1  = rbB[lane];
    const float det = fmaf(P00, P11, -P01 * P01);
    const float idet = __builtin_amdgcn_rcpf(det);
    ld += __log2f(det);
    const float Pi00 =  P11 * idet;
    const float Pi01 = -P01 * idet;
    const float Pi11 =  P00 * idet;

    const bool isp = (lane == p), isq = (lane == p + 1);
    const float w0 = isp ? Pi00 : (isq ? Pi01 : fmaf(Pi00, a0, Pi01 * a1));
    const float w1 = isp ? Pi01 : (isq ? Pi11 : fmaf(Pi01, a0, Pi11 * a1));
    const float t0 = isp ? (1.f - w0) : (isq ? -w0 : w0);
    const float t1 = isq ? (1.f - w1) : (isp ? -w1 : w1);
    const float f0 = (isp || isq) ? -w0 : w0;
    const float f1 = (isp || isq) ? -w1 : w1;

    // early-publish next step's pivot rows (same value the main loop will
    // recompute for these regs — publish-only, no restore needed)
    if (s < 31 && wave == own_s1) {
      const float e0 = fmaf(-t1, rbB[p + 2], fmaf(-t0, rbA[p + 2], reg[rp2]));
      const float e1 = fmaf(-t1, rbB[p + 3], fmaf(-t0, rbA[p + 3], reg[rp2 + 1]));
      rowbuf[par ^ 1][0][lane] = e0;
      rowbuf[par ^ 1][1][lane] = e1;
    }

    const float4* rAq = reinterpret_cast<const float4*>(rbA + 16 * wave);
    const float4* rBq = reinterpret_cast<const float4*>(rbB + 16 * wave);
#pragma unroll
    for (int q = 0; q < 4; q++) {
      const float4 va = rAq[q], vb = rBq[q];
      reg[4 * q + 0] = fmaf(-t1, vb.x, fmaf(-t0, va.x, reg[4 * q + 0]));
      reg[4 * q + 1] = fmaf(-t1, vb.y, fmaf(-t0, va.y, reg[4 * q + 1]));
      reg[4 * q + 2] = fmaf(-t1, vb.z, fmaf(-t0, va.z, reg[4 * q + 2]));
      reg[4 * q + 3] = fmaf(-t1, vb.w, fmaf(-t0, va.w, reg[4 * q + 3]));
    }
    if (wave == own_s) { reg[rp] = f0; reg[rp + 1] = f1; }
    __syncthreads();
  }
  return ld;
}

// ---------------------------------------------------------------------------
// K1: 10 blocks. b<8: prep. b==8: Kuu^{-1} pipelined sweep. b==9: YY + KL.
// Block 0 zeroes the 32 barrier ints (K2 is stream-ordered after K1).
// ---------------------------------------------------------------------------
__global__ __launch_bounds__(256) void vdmgp_k1(
    const float* __restrict__ X, const float* __restrict__ Y,
    const float* __restrict__ qmu, const float* __restrict__ qcov,
    const float* __restrict__ Z, float* __restrict__ ws) {
  __shared__ float smu[D_ * K_];   // [d][k]
  __shared__ float scov[D_ * K_];
  __shared__ float zl[M_][9];
  __shared__ __align__(16) float rowbuf[2][2][M_];
  const int tid = threadIdx.x;
  const int b = blockIdx.x;

  if (b == 0 && tid < 32) ((int*)ws)[tid] = 0;

  if (b == 8) {
    for (int idx = tid; idx < M_ * K_; idx += 256) zl[idx >> 3][idx & 7] = Z[idx];
    __syncthreads();
    const int lane = tid & 63;
    const int wave = tid >> 6;
    float zj[K_];
#pragma unroll
    for (int k = 0; k < K_; k++) zj[k] = zl[lane][k];
    float reg[16];
#pragma unroll
    for (int r = 0; r < 16; r++) {
      const int gi = 16 * wave + r;
      float sq = 0.f;
#pragma unroll
      for (int k = 0; k < K_; k++) { const float dd = zl[gi][k] - zj[k]; sq = fmaf(dd, dd, sq); }
      reg[r] = exp2f(-0.5f * L2E * sq) + ((gi == lane) ? JIT : 0.f);
    }
    const float ld1 = sweep2x2_pipe(reg, rowbuf, wave, lane);
#pragma unroll
    for (int r = 0; r < 16; r++)
      ws[OFF_KUI + (16 * wave + r) * 64 + lane] = reg[r];   // -Kuu^{-1}
    if (tid == 0) ws[OFF_SC + 2] = LN2 * ld1;
    return;
  }

  if (b == 9) {
    const int lane = tid & 63;
    const int wave = tid >> 6;
    if (wave == 0) {
      float yy = 0.f;
#pragma unroll
      for (int t = 0; t < 32; t++) {
        const float y = Y[t * 64 + lane];
        yy = fmaf(y, y, yy);
      }
#pragma unroll
      for (int off = 32; off > 0; off >>= 1) yy += __shfl_down(yy, off, 64);
      if (lane == 0) ws[OFF_SC + 0] = yy;
    } else if (wave == 1) {
      const int k = lane >> 3;
      const int d0 = (lane & 7) * 16;
      float slog = 0.f, srow = 0.f;
#pragma unroll
      for (int t = 0; t < 16; t++) {
        const float qc = qcov[k * D_ + d0 + t];
        const float qm = qmu[k * D_ + d0 + t];
        slog += logf(qc);
        srow += qc + qm * qm;
      }
#pragma unroll
      for (int off = 4; off > 0; off >>= 1) {
        slog += __shfl_down(slog, off, 8);
        srow += __shfl_down(srow, off, 8);
      }
      float klr = ((lane & 7) == 0)
          ? (slog - (float)D_ * logf(srow) + (float)D_ * logf((float)D_)) : 0.f;
      klr += __shfl_down(klr, 32, 64);
      klr += __shfl_down(klr, 16, 64);
      klr += __shfl_down(klr, 8, 64);
      if (lane == 0) ws[OFF_SC + 1] = klr;
    }
    return;
  }

  // prep: one n per thread
  for (int idx = tid; idx < K_ * D_; idx += 256) {
    int k = idx >> 7, d = idx & 127;
    smu[d * K_ + k]  = qmu[idx];
    scov[d * K_ + k] = qcov[idx];
  }
  __syncthreads();

  const int n = b * 256 + tid;
  float a[K_], s2[K_];
#pragma unroll
  for (int k = 0; k < K_; k++) { a[k] = 0.f; s2[k] = 0.f; }

  const float4* xrow = reinterpret_cast<const float4*>(X + n * D_);
#pragma unroll 2
  for (int dq = 0; dq < D_ / 4; dq++) {
    float4 xv = xrow[dq];
    float xs[4] = {xv.x, xv.y, xv.z, xv.w};
#pragma unroll
    for (int t = 0; t < 4; t++) {
      const int d = dq * 4 + t;
      const float x = xs[t];
      const float xx = x * x;
      F8 mu = *reinterpret_cast<const F8*>(&smu[d * K_]);
      F8 cv = *reinterpret_cast<const F8*>(&scov[d * K_]);
#pragma unroll
      for (int k = 0; k < K_; k++) {
        a[k]  = fmaf(mu.f[k], x, a[k]);
        s2[k] = fmaf(cv.f[k], xx, s2[k]);
      }
    }
  }

  float4 w2[4], w1[4];
  float prod2 = 1.f, prod1 = 1.f;
#pragma unroll
  for (int k = 0; k < K_; k++) {
    const float b2 = 2.f * s2[k] + 1.f;
    const float b1 = 1.f + s2[k];
    reinterpret_cast<float*>(w2)[k]     = a[k];
    reinterpret_cast<float*>(w2)[8 + k] = L2E / b2;
    reinterpret_cast<float*>(w1)[k]     = a[k];
    reinterpret_cast<float*>(w1)[8 + k] = 0.5f * L2E / b1;
    prod2 *= rsqrtf(b2);
    prod1 *= rsqrtf(b1);
  }
  float4* a2q = reinterpret_cast<float4*>(ws + OFF_ARR2 + n * 16);
  float4* a1q = reinterpret_cast<float4*>(ws + OFF_ARR1 + n * 16);
#pragma unroll
  for (int e = 0; e < 4; e++) { a2q[e] = w2[e]; a1q[e] = w1[e]; }
  (ws + OFF_C2)[n] = prod2;
  (ws + OFF_CY)[n] = prod1 * Y[n];
}

// ---------------------------------------------------------------------------
// K2: 257 blocks.
//   b==0        : tail. Preload zl, A2's Kuu part, -Kuu^{-1} cols (registers)
//                 -> wait bar[17]=16 -> p2v from ws (regs) -> trace partial ->
//                 pipelined A2 sweep -> wait bar[16]=8 -> quad -> combine.
//   b>=1, t=b-1 : psi2 task (chunk t>>4, pairblk t&15) -> arrive bar[t&15].
//                 t<16 : wait bar[t]=16, reduce slice t -> arrive bar[17].
//                 16<=t<24 : Psi1^T Y chunk (t-16) -> arrive bar[16].
// ---------------------------------------------------------------------------
__global__ __launch_bounds__(256) void vdmgp_k2(
    const float* __restrict__ Z,
    const float* __restrict__ sfp, const float* __restrict__ nvp,
    float* __restrict__ ws, float* __restrict__ out) {
  __shared__ __align__(16) float pool[4864];

  int* bar = (int*)ws;
  const int tid = threadIdx.x;
  const int b = blockIdx.x;
  const float sf = sfp[0];

  if (b > 0) {
    const int t = b - 1;
    // -------- psi2 task (x4-unrolled inner loop) --------
    {
      float* sa = pool;           // 128*16
      float* sc = pool + 2048;    // 128
      const int chunk = t >> 4;
      const int nbase = chunk * 128;
      const float4* src = reinterpret_cast<const float4*>(ws + OFF_ARR2 + nbase * 16);
      float4* dst = reinterpret_cast<float4*>(sa);
      for (int idx = tid; idx < 128 * 4; idx += 256) dst[idx] = src[idx];
      if (tid < 128) sc[tid] = (ws + OFF_C2)[nbase + tid];
      __syncthreads();

      const int pair = (t & 15) * 256 + tid;
      const int i = pair >> 6, j = pair & 63;
      float zb[K_];
#pragma unroll
      for (int k = 0; k < K_; k++) zb[k] = 0.5f * (Z[i * K_ + k] + Z[j * K_ + k]);

      float acc = 0.f;
      for (int nl = 0; nl < 128; nl += 4) {
        F8 av0 = *reinterpret_cast<const F8*>(&sa[(nl + 0) * 16]);
        F8 ib0 = *reinterpret_cast<const F8*>(&sa[(nl + 0) * 16 + 8]);
        F8 av1 = *reinterpret_cast<const F8*>(&sa[(nl + 1) * 16]);
        F8 ib1 = *reinterpret_cast<const F8*>(&sa[(nl + 1) * 16 + 8]);
        F8 av2 = *reinterpret_cast<const F8*>(&sa[(nl + 2) * 16]);
        F8 ib2 = *reinterpret_cast<const F8*>(&sa[(nl + 2) * 16 + 8]);
        F8 av3 = *reinterpret_cast<const F8*>(&sa[(nl + 3) * 16]);
        F8 ib3 = *reinterpret_cast<const F8*>(&sa[(nl + 3) * 16 + 8]);
        float s0 = 0.f, s1 = 0.f, s2 = 0.f, s3 = 0.f;
#pragma unroll
        for (int k = 0; k < K_; k++) {
          const float d0 = av0.f[k] - zb[k]; s0 = fmaf(d0 * d0, ib0.f[k], s0);
          const float d1 = av1.f[k] - zb[k]; s1 = fmaf(d1 * d1, ib1.f[k], s1);
          const float d2 = av2.f[k] - zb[k]; s2 = fmaf(d2 * d2, ib2.f[k], s2);
          const float d3 = av3.f[k] - zb[k]; s3 = fmaf(d3 * d3, ib3.f[k], s3);
        }
        acc = fmaf(sc[nl + 0], exp2f(-s0), acc);
        acc = fmaf(sc[nl + 1], exp2f(-s1), acc);
        acc = fmaf(sc[nl + 2], exp2f(-s2), acc);
        acc = fmaf(sc[nl + 3], exp2f(-s3), acc);
      }
      (ws + OFF_P2P)[chunk * 4096 + (t & 15) * 256 + tid] = acc;
    }
    bar_arrive(&bar[t & 15]);

    if (t < 16) {
      // -------- reduce slice t: pairs [256t, 256t+256) --------
      bar_wait<4>(&bar[t], 16);
      const int p = t * 256 + tid;
      float acc = 0.f;
#pragma unroll
      for (int c = 0; c < 16; c++) acc += ws[OFF_P2P + c * 4096 + p];
      const int i = p >> 6, j = p & 63;
      float sq = 0.f;
#pragma unroll
      for (int k = 0; k < K_; k++) {
        const float dd = Z[i * K_ + k] - Z[j * K_ + k];
        sq = fmaf(dd, dd, sq);
      }
      ws[OFF_PSI2 + p] = sf * sf * exp2f(-0.25f * L2E * sq) * acc;
      bar_arrive(&bar[17]);
    } else if (t < 24) {
      // -------- Psi1^T Y chunk (t-16) --------
      float* sa1 = pool;          // 256*16
      float* scy = pool + 4096;   // 256
      float* red = pool + 4352;   // 256
      const int chunk = t - 16;
      const int nbase = chunk * 256;
      const float4* src = reinterpret_cast<const float4*>(ws + OFF_ARR1 + nbase * 16);
      float4* dst = reinterpret_cast<float4*>(sa1);
#pragma unroll
      for (int r = 0; r < 4; r++) dst[r * 256 + tid] = src[r * 256 + tid];
      scy[tid] = (ws + OFF_CY)[nbase + tid];
      __syncthreads();

      const int m = tid & 63;
      const int stripe = tid >> 6;
      float zm[K_];
#pragma unroll
      for (int k = 0; k < K_; k++) zm[k] = Z[m * K_ + k];

      float acc = 0.f;
      for (int u = 0; u < 64; u++) {
        const int nl = stripe * 64 + u;
        const F8 av = *reinterpret_cast<const F8*>(&sa1[nl * 16]);
        const F8 ib = *reinterpret_cast<const F8*>(&sa1[nl * 16 + 8]);
        float s = 0.f;
#pragma unroll
        for (int k = 0; k < K_; k++) {
          const float d = av.f[k] - zm[k];
          s = fmaf(d * d, ib.f[k], s);
        }
        acc = fmaf(scy[nl], exp2f(-s), acc);
      }
      red[tid] = acc;
      __syncthreads();
      if (tid < 64)
        (ws + OFF_P1Y)[chunk * 64 + tid] =
            red[tid] + red[64 + tid] + red[128 + tid] + red[192 + tid];
      bar_arrive(&bar[16]);
    }
    return;
  }

  // -------- b == 0: tail --------
  float (*zl)[9]         = reinterpret_cast<float(*)[9]>(pool);            // 576
  float (*rowbuf)[2][M_] = reinterpret_cast<float(*)[2][M_]>(pool + 576);  // 256
  float* pysL  = pool + 832;                                               // 64
  float* scalL = pool + 896;                                               // 8
  float* redQ  = pool + 912;                                               // 256
  float* redT  = pool + 1168;                                              // 256

  const int lane = tid & 63;
  const int wave = tid >> 6;
  const float s2v = nvp[0];

  for (int idx = tid; idx < M_ * K_; idx += 256) zl[idx >> 3][idx & 7] = Z[idx];
  __syncthreads();

  // preload (off critical path): A2's Kuu part and -Kuu^{-1} column slices
  float zj[K_];
#pragma unroll
  for (int k = 0; k < K_; k++) zj[k] = zl[lane][k];
  float base[16], kui16[16];
#pragma unroll
  for (int r = 0; r < 16; r++) {
    const int gi = 16 * wave + r;
    float sq = 0.f;
#pragma unroll
    for (int k = 0; k < K_; k++) { const float dd = zl[gi][k] - zj[k]; sq = fmaf(dd, dd, sq); }
    const float jit = (gi == lane) ? JIT : 0.f;
    base[r] = fmaf(s2v, exp2f(-0.5f * L2E * sq) + jit, jit);
    kui16[r] = ws[OFF_KUI + gi * 64 + lane];
  }

  bar_wait<2>(&bar[17], 16);    // reduced psi2 ready

  float reg[16];
  float sT = 0.f;
#pragma unroll
  for (int r = 0; r < 16; r++) {
    const int gi = 16 * wave + r;
    const float p2v = ws[OFF_PSI2 + gi * 64 + lane];
    reg[r] = base[r] + p2v;
    sT = fmaf(kui16[r], p2v, sT);
  }
  redT[tid] = sT;

  const float ld2 = sweep2x2_pipe(reg, rowbuf, wave, lane);

  bar_wait<2>(&bar[16], 8);     // p1y ready (normally long done)
  if (tid < M_) {
    float s = 0.f;
#pragma unroll
    for (int c = 0; c < 8; c++) s += ws[OFF_P1Y + c * M_ + tid];
    pysL[tid] = sf * s;
  }
  __syncthreads();

  float sQ = 0.f;
#pragma unroll
  for (int r = 0; r < 16; r++) sQ = fmaf(reg[r], pysL[16 * wave + r], sQ);
  redQ[tid] = sQ;
  __syncthreads();

  if (wave == 0) {
    float c = redQ[lane] + redQ[64 + lane] + redQ[128 + lane] + redQ[192 + lane];
    float q = c * pysL[lane];
#pragma unroll
    for (int off = 32; off > 0; off >>= 1) q += __shfl_down(q, off, 64);
    if (lane == 0) scalL[7] = -q;    // quad
  } else if (wave == 1) {
    float s = redT[lane] + redT[64 + lane] + redT[128 + lane] + redT[192 + lane];
#pragma unroll
    for (int off = 32; off > 0; off >>= 1) s += __shfl_down(s, off, 64);
    if (lane == 0) scalL[5] = -s;    // trace
  }
  __syncthreads();

  if (tid == 0) {
    const float YY  = ws[OFF_SC + 0];
    const float KL  = ws[OFF_SC + 1];
    const float ld1 = ws[OFF_SC + 2];
    const float tr = scalL[5], quad = scalL[7];
    const float inv = 1.0f / s2v;
    const float F1 = -(float)N_ * 1.8378770664093453f
                   - (float)(N_ - M_) * logf(s2v)
                   + (ld1 - LN2 * ld2)
                   - YY * inv
                   + quad * inv
                   - (float)N_ * sf * sf * inv
                   + tr * inv;
    out[0] = 0.5f * (F1 + KL);
  }
}

extern "C" void kernel_launch(void* const* d_in, const int* in_sizes, int n_in,
                              void* d_out, int out_size, void* d_ws, size_t ws_size,
                              hipStream_t stream) {
  const float* X    = (const float*)d_in[0];
  const float* Y    = (const float*)d_in[1];
  const float* qmu  = (const float*)d_in[2];
  const float* qcov = (const float*)d_in[3];
  const float* Z    = (const float*)d_in[4];
  const float* sfp  = (const float*)d_in[5];
  const float* nvp  = (const float*)d_in[6];
  float* ws  = (float*)d_ws;
  float* out = (float*)d_out;

  vdmgp_k1<<<10, 256, 0, stream>>>(X, Y, qmu, qcov, Z, ws);
  vdmgp_k2<<<257, 256, 0, stream>>>(Z, sfp, nvp, ws, out);
}